// Round 16
// baseline (216.459 us; speedup 1.0000x reference)
//
#include <hip/hip_runtime.h>

#define BB 128
#define NN 8192
#define SS 100
#define KK 512
#define SPB 10                 // samples per block, pipelined 1-deep
#define SPLIT (SS / SPB)       // 10 chunks per batch row
#define NT 1024                // 16 waves
#define EPT 8                  // elements per thread per sample
#define CAND 512
#define NBIN 2048
#define NWAVE 16

#define GIDX(e) (((e) >> 2) * 4096 + tid * 4 + ((e) & 3))
#define LN2 0.69314718056f

// LDS-only barrier: waits DS ops but leaves global loads in flight
// (__syncthreads drains vmcnt(0) too — guide §5). sched_barrier stops the
// compiler hoisting LDS reads above the wait (guide rule #18).
__device__ __forceinline__ void lds_barrier() {
    asm volatile("s_waitcnt lgkmcnt(0)" ::: "memory");
    __builtin_amdgcn_s_barrier();
    __builtin_amdgcn_sched_barrier(0);
}

// q-key: q = (-ln(u+eps)+eps) * e^{-lg} = e^{-p}, monotone DECREASING in p.
// ONE transcendental per element-sample; e^{-lg} precomputed per logit.
__device__ __forceinline__ float q_of(float u, float elg) {
    const float w = fmaf(__builtin_amdgcn_logf(u + 1e-20f), -LN2, 1e-20f);
    return w * elg;
}

// Monotone bin map via float bits (sign|exp8|mant7), flipped so HIGHER bin =
// HIGHER p. Window q in [2^-13,16) i.e. p in (-2.77, 9]; outside clamps, and
// clamped bins stay exact via the in-bin rank loop (exact q compares).
__device__ __forceinline__ int bin_of(float q) {
    const int t = (int)(__float_as_uint(q) >> 16);
    int b = 16639 - t;
    b = b < 0 ? 0 : b;
    return b > 2047 ? 2047 : b;
}

// elg[i] = e^{-logits[i]} (one v_exp per logit, reused over 100 samples)
__global__ __launch_bounds__(256) void exp_kernel(
    const float* __restrict__ logits, float* __restrict__ elg) {
    const int i = blockIdx.x * 256 + threadIdx.x;
    const float4 v = reinterpret_cast<const float4*>(logits)[i];
    float4 o;
    o.x = __expf(-v.x); o.y = __expf(-v.y);
    o.z = __expf(-v.z); o.w = __expf(-v.w);
    reinterpret_cast<float4*>(elg)[i] = o;
}

// One block = (b, 10 samples). Ping-pong register prefetch: sample s+1's
// loads are issued before sample s's phases and survive every lds_barrier,
// so VMEM stays busy through the compute phases. 4 barriers/sample.
// MODE 0: 8 x u8 counts (2 u32/thread) -> ws. MODE 1: atomicAdd out.
template <int MODE>
__global__ __launch_bounds__(NT, 8) void gumbel_topk_kernel(
    const float* __restrict__ elg_or_logits,
    const float* __restrict__ uniform,
    unsigned* __restrict__ ws,
    float* __restrict__ out) {

    __shared__ __align__(16) int hist[NBIN];
    __shared__ float ck[CAND];
    __shared__ int   ci[CAND];
    __shared__ int   waveTot[NWAVE];
    __shared__ int   bsel, bkk, cnt;

    const int tid  = threadIdx.x;
    const int lane = tid & 63;
    const int wv   = tid >> 6;
    const int b    = blockIdx.x / SPLIT;
    const int ch   = blockIdx.x % SPLIT;

    const float* erow  = elg_or_logits + (size_t)b * NN;
    const float* u0row = uniform + ((size_t)b * SS + ch * SPB) * NN;

    auto loadSample = [&](float (&dst)[EPT], int s) {
#pragma unroll
        for (int j = 0; j < 2; ++j)
            *reinterpret_cast<float4*>(&dst[j * 4]) =
                *reinterpret_cast<const float4*>(
                    &u0row[(size_t)s * NN + j * 4096 + tid * 4]);
    };

    // ---- issue elg + sample-0 loads upfront; in flight across s0
    float le[EPT], bufA[EPT], bufB[EPT];
#pragma unroll
    for (int j = 0; j < 2; ++j)
        *reinterpret_cast<float4*>(&le[j * 4]) =
            *reinterpret_cast<const float4*>(&erow[j * 4096 + tid * 4]);
    loadSample(bufA, 0);
    if (MODE == 1) {
#pragma unroll
        for (int e = 0; e < EPT; ++e) le[e] = __expf(-le[e]);
    }

    // ---- init LDS: 2048 ints over 1024 threads = one int2 each
    *reinterpret_cast<int2*>(&hist[tid * 2]) = make_int2(0, 0);
    if (tid == 0) cnt = 0;
    lds_barrier();                                        // s0

    unsigned c8lo = 0, c8hi = 0;    // 8 x u8 membership counts (max 10)

    auto processSample = [&](float (&cur)[EPT]) {
        // ---- transform (1 log/elem) + histogram; q stays live in cur
#pragma unroll
        for (int e = 0; e < EPT; ++e) {
            cur[e] = q_of(cur[e], le[e]);
            atomicAdd(&hist[bin_of(cur[e])], 1);
        }
        lds_barrier();                                    // s1

        // ---- scan: read own 2 bins, RE-ZERO (ready for next sample),
        // cross-wave suffix scan
        const int base = tid * 2;
        const int2 h = *reinterpret_cast<const int2*>(&hist[base]);
        *reinterpret_cast<int2*>(&hist[base]) = make_int2(0, 0);
        const int sum = h.x + h.y;
        int suf = sum;
#pragma unroll
        for (int d = 1; d < 64; d <<= 1) {
            const int o = __shfl_down(suf, d);
            if (lane + d < 64) suf += o;
        }
        if (lane == 0) waveTot[wv] = suf;
        lds_barrier();                                    // s2

        // ---- locate threshold bin; crossing thread broadcasts
        int cum = suf - sum;
        for (int w2 = wv + 1; w2 < NWAVE; ++w2) cum += waveTot[w2];
        if (cum < KK && cum + h.y >= KK) { bsel = base + 1; bkk = KK - cum; }
        cum += h.y;
        if (cum < KK && cum + h.x >= KK) { bsel = base;     bkk = KK - cum; }
        if (tid == 0) cnt = 0;     // safe: last readers finished before s1
        lds_barrier();                                    // s3

        const int sel = bsel, kk = bkk;

        // ---- collect threshold-bin candidates (~3-6 expected; keys live)
#pragma unroll
        for (int e = 0; e < EPT; ++e) {
            if (bin_of(cur[e]) == sel) {
                const int pos = atomicAdd(&cnt, 1);
                if (pos < CAND) { ck[pos] = cur[e]; ci[pos] = GIDX(e); }
            }
        }
        lds_barrier();                                    // s4

        // ---- membership: in-bin elements rank by (q asc = p desc, idx asc)
        const int c = cnt < CAND ? cnt : CAND;
#pragma unroll
        for (int e = 0; e < EPT; ++e) {
            const int bb = bin_of(cur[e]);
            int in = 0;
            if (bb > sel) {
                in = 1;
            } else if (bb == sel) {
                const float kl = cur[e]; const int il = GIDX(e);
                int r = 0;
                for (int j = 0; j < c; ++j)
                    r += (ck[j] < kl || (ck[j] == kl && ci[j] < il)) ? 1 : 0;
                in = (r < kk);
            }
            if (in) {
                if (e < 4) c8lo += 1u << (8 * e);
                else       c8hi += 1u << (8 * (e - 4));
            }
        }
        // no trailing barrier: next sample's hist atomics are gated by this
        // sample's s1..s4 having cleared all cross-thread dependencies.
    };

    // ---- ping-pong schedule: next sample's loads issued before current's
    // phases; they survive all barriers (lgkmcnt-only waits).
    for (int s = 0; s < SPB; s += 2) {
        loadSample(bufB, s + 1);
        processSample(bufA);
        if (s + 2 < SPB) loadSample(bufA, s + 2);
        processSample(bufB);
    }

    if (MODE == 0) {
        uint2* wsrow = reinterpret_cast<uint2*>(ws + (size_t)blockIdx.x * (NT * 2));
        wsrow[tid] = make_uint2(c8lo, c8hi);
    } else {
        float* orow = out + (size_t)b * NN;
#pragma unroll
        for (int e = 0; e < EPT; ++e) {
            const unsigned cc = (e < 4 ? (c8lo >> (8 * e)) : (c8hi >> (8 * (e - 4)))) & 0xFFu;
            if (cc) atomicAdd(orow + GIDX(e), (float)cc * 0.01f);
        }
    }
}

// Sum 10 u8-packed partials per u32 slot (each byte <= 10, sum <= 100).
// Slot = tid*2 + w covers elements e = 4w..4w+3 -> gidx = w*4096 + t*4 + i.
__global__ __launch_bounds__(256) void reduce_kernel(
    const unsigned* __restrict__ ws, float* __restrict__ out) {
    const int g    = blockIdx.x * 256 + threadIdx.x;   // 0..262143
    const int b    = g >> 11;
    const int slot = g & 2047;
    const int t    = slot >> 1;
    const int w    = slot & 1;
    unsigned acc = 0;
    for (int c = 0; c < SPLIT; ++c)
        acc += ws[((size_t)(b * SPLIT + c) << 11) + slot];
    const float4 o = make_float4((float)(acc & 255u) * 0.01f,
                                 (float)((acc >> 8) & 255u) * 0.01f,
                                 (float)((acc >> 16) & 255u) * 0.01f,
                                 (float)(acc >> 24) * 0.01f);
    *reinterpret_cast<float4*>(out + (size_t)b * NN + w * 4096 + t * 4) = o;
}

extern "C" void kernel_launch(void* const* d_in, const int* in_sizes, int n_in,
                              void* d_out, int out_size, void* d_ws, size_t ws_size,
                              hipStream_t stream) {
    const float* logits  = (const float*)d_in[0];   // [128, 8192] f32
    const float* uniform = (const float*)d_in[1];   // [128, 100, 8192] f32
    float* out = (float*)d_out;                     // [128, 8192] f32

    const int grid = BB * SPLIT;                    // 1280 blocks
    const size_t elgBytes = (size_t)BB * NN * sizeof(float);            // 4 MB
    const size_t cntBytes = (size_t)grid * NT * 2 * sizeof(unsigned);   // 10.5 MB

    if (ws_size >= elgBytes + cntBytes) {
        float* elg = (float*)d_ws;
        unsigned* cnts = (unsigned*)((char*)d_ws + elgBytes);
        exp_kernel<<<(BB * NN / 4) / 256, 256, 0, stream>>>(logits, elg);
        gumbel_topk_kernel<0><<<grid, NT, 0, stream>>>(
            elg, uniform, cnts, nullptr);
        reduce_kernel<<<(BB * NN / 4) / 256, 256, 0, stream>>>(cnts, out);
    } else {
        hipMemsetAsync(out, 0, (size_t)out_size * sizeof(float), stream);
        gumbel_topk_kernel<1><<<grid, NT, 0, stream>>>(
            logits, uniform, nullptr, out);
    }
}

// Round 17
// 198.986 us; speedup vs baseline: 1.0878x; 1.0878x over previous
//
#include <hip/hip_runtime.h>

#define BB 128
#define NN 8192
#define SS 100
#define KK 512
#define SPB 10                 // samples per block, LDS-staged 2-deep
#define SPLIT (SS / SPB)       // 10 chunks per batch row
#define NT 1024                // 16 waves
#define EPT 8                  // elements per thread per sample
#define CAND 512
#define NBIN 2048
#define NWAVE 16

#define GIDX(e) (((e) >> 2) * 4096 + tid * 4 + ((e) & 3))
#define LN2 0.69314718056f

// LDS-only barrier: waits DS ops but leaves global/stage loads in flight
// (__syncthreads drains vmcnt(0) too — guide §5). sched_barrier stops the
// compiler hoisting LDS reads above the wait (guide rule #18).
__device__ __forceinline__ void lds_barrier() {
    asm volatile("s_waitcnt lgkmcnt(0)" ::: "memory");
    __builtin_amdgcn_s_barrier();
    __builtin_amdgcn_sched_barrier(0);
}

// q-key: q = (-ln(u+eps)+eps) * e^{-lg} = e^{-p}, monotone DECREASING in p.
// ONE transcendental per element-sample; e^{-lg} precomputed per logit.
__device__ __forceinline__ float q_of(float u, float elg) {
    const float w = fmaf(__builtin_amdgcn_logf(u + 1e-20f), -LN2, 1e-20f);
    return w * elg;
}

// Monotone bin map via float bits (sign|exp8|mant7), flipped so HIGHER bin =
// HIGHER p. Window q in [2^-13,16) i.e. p in (-2.77, 9]; outside clamps, and
// clamped bins stay exact via the in-bin rank loop (exact q compares).
__device__ __forceinline__ int bin_of(float q) {
    const int t = (int)(__float_as_uint(q) >> 16);
    int b = 16639 - t;
    b = b < 0 ? 0 : b;
    return b > 2047 ? 2047 : b;
}

// async global->LDS, 16B per lane; LDS dest = base + lane*16 (HW rule)
__device__ __forceinline__ void gload_lds16(const float* g, float* l) {
    __builtin_amdgcn_global_load_lds(
        (const __attribute__((address_space(1))) unsigned int*)(g),
        (__attribute__((address_space(3))) unsigned int*)(l),
        16, 0, 0);
}

// elg[i] = e^{-logits[i]} (one v_exp per logit, reused over 100 samples)
__global__ __launch_bounds__(256) void exp_kernel(
    const float* __restrict__ logits, float* __restrict__ elg) {
    const int i = blockIdx.x * 256 + threadIdx.x;
    const float4 v = reinterpret_cast<const float4*>(logits)[i];
    float4 o;
    o.x = __expf(-v.x); o.y = __expf(-v.y);
    o.z = __expf(-v.z); o.w = __expf(-v.w);
    reinterpret_cast<float4*>(elg)[i] = o;
}

// One block = (b, 10 samples). Sample u-rows are staged into LDS via
// global_load_lds (no VGPR cost), 2 samples in flight, counted vmcnt waits.
// Each wave consumes ONLY the stage chunks it issued -> stage sync is
// wave-local (no barriers). Hist phases keep the R14 4-barrier structure.
// MODE 0: 8 x u8 counts (2 u32/thread) -> ws. MODE 1: atomicAdd out.
template <int MODE>
__global__ __launch_bounds__(NT, 8) void gumbel_topk_kernel(
    const float* __restrict__ elg_or_logits,
    const float* __restrict__ uniform,
    unsigned* __restrict__ ws,
    float* __restrict__ out) {

    __shared__ __align__(16) float stage[2][NN];   // 64 KB
    __shared__ __align__(16) int hist[NBIN];       // 8 KB
    __shared__ float ck[CAND];
    __shared__ int   ci[CAND];
    __shared__ int   waveTot[NWAVE];
    __shared__ int   bsel, bkk, cnt;

    const int tid  = threadIdx.x;
    const int lane = tid & 63;
    const int wv   = tid >> 6;
    const int b    = blockIdx.x / SPLIT;
    const int ch   = blockIdx.x % SPLIT;

    const float* erow  = elg_or_logits + (size_t)b * NN;
    const float* u0row = uniform + ((size_t)b * SS + ch * SPB) * NN;

    // stage sample s into buffer s&1: per wave 2 instrs, 1 KB each, linear
    auto issueStage = [&](int s) {
#pragma unroll
        for (int k = 0; k < 2; ++k)
            gload_lds16(u0row + (size_t)s * NN + k * 4096 + wv * 256 + lane * 4,
                        &stage[s & 1][k * 4096 + wv * 256]);
    };

    // ---- issue elg (reg) + stages for samples 0,1; all stay in flight
    float le[EPT];
#pragma unroll
    for (int j = 0; j < 2; ++j)
        *reinterpret_cast<float4*>(&le[j * 4]) =
            *reinterpret_cast<const float4*>(&erow[j * 4096 + tid * 4]);
    issueStage(0);
    issueStage(1);
    if (MODE == 1) {
#pragma unroll
        for (int e = 0; e < EPT; ++e) le[e] = __expf(-le[e]);
    }

    // ---- init LDS hist
    *reinterpret_cast<int2*>(&hist[tid * 2]) = make_int2(0, 0);
    if (tid == 0) cnt = 0;
    lds_barrier();                                        // s0

    unsigned c8lo = 0, c8hi = 0;    // 8 x u8 membership counts (max 10)

    for (int s = 0; s < SPB; ++s) {
        // ---- wave-local: wait own stage(s) complete (2 loads of stage(s+1)
        // may remain in flight); last sample waits everything.
        if (s + 1 < SPB) asm volatile("s_waitcnt vmcnt(2)" ::: "memory");
        else             asm volatile("s_waitcnt vmcnt(0)" ::: "memory");
        __builtin_amdgcn_sched_barrier(0);

        // ---- read own chunk from LDS, retire reads, re-issue buffer
        float q[EPT];
#pragma unroll
        for (int j = 0; j < 2; ++j)
            *reinterpret_cast<float4*>(&q[j * 4]) =
                *reinterpret_cast<const float4*>(&stage[s & 1][j * 4096 + tid * 4]);
        asm volatile("s_waitcnt lgkmcnt(0)" ::: "memory");
        __builtin_amdgcn_sched_barrier(0);
        if (s + 2 < SPB) issueStage(s + 2);

        // ---- transform (1 log/elem) + histogram
#pragma unroll
        for (int e = 0; e < EPT; ++e) {
            q[e] = q_of(q[e], le[e]);
            atomicAdd(&hist[bin_of(q[e])], 1);
        }
        lds_barrier();                                    // s1

        // ---- scan: read own 2 bins, RE-ZERO, cross-wave suffix scan
        const int base = tid * 2;
        const int2 h = *reinterpret_cast<const int2*>(&hist[base]);
        *reinterpret_cast<int2*>(&hist[base]) = make_int2(0, 0);
        const int sum = h.x + h.y;
        int suf = sum;
#pragma unroll
        for (int d = 1; d < 64; d <<= 1) {
            const int o = __shfl_down(suf, d);
            if (lane + d < 64) suf += o;
        }
        if (lane == 0) waveTot[wv] = suf;
        lds_barrier();                                    // s2

        // ---- locate threshold bin; crossing thread broadcasts
        int cum = suf - sum;
        for (int w2 = wv + 1; w2 < NWAVE; ++w2) cum += waveTot[w2];
        if (cum < KK && cum + h.y >= KK) { bsel = base + 1; bkk = KK - cum; }
        cum += h.y;
        if (cum < KK && cum + h.x >= KK) { bsel = base;     bkk = KK - cum; }
        if (tid == 0) cnt = 0;     // safe: last readers finished before s1
        lds_barrier();                                    // s3

        const int sel = bsel, kk = bkk;

        // ---- collect threshold-bin candidates (~3-6 expected; keys live)
#pragma unroll
        for (int e = 0; e < EPT; ++e) {
            if (bin_of(q[e]) == sel) {
                const int pos = atomicAdd(&cnt, 1);
                if (pos < CAND) { ck[pos] = q[e]; ci[pos] = GIDX(e); }
            }
        }
        lds_barrier();                                    // s4

        // ---- membership: in-bin elements rank by (q asc = p desc, idx asc)
        const int c = cnt < CAND ? cnt : CAND;
#pragma unroll
        for (int e = 0; e < EPT; ++e) {
            const int bb = bin_of(q[e]);
            int in = 0;
            if (bb > sel) {
                in = 1;
            } else if (bb == sel) {
                const float kl = q[e]; const int il = GIDX(e);
                int r = 0;
                for (int j = 0; j < c; ++j)
                    r += (ck[j] < kl || (ck[j] == kl && ci[j] < il)) ? 1 : 0;
                in = (r < kk);
            }
            if (in) {
                if (e < 4) c8lo += 1u << (8 * e);
                else       c8hi += 1u << (8 * (e - 4));
            }
        }
        // no trailing barrier: next hist atomics only touch hist (zeroed at
        // s2-phase); ck/ci rewritten only after the NEXT s3.
    }

    if (MODE == 0) {
        uint2* wsrow = reinterpret_cast<uint2*>(ws + (size_t)blockIdx.x * (NT * 2));
        wsrow[tid] = make_uint2(c8lo, c8hi);
    } else {
        float* orow = out + (size_t)b * NN;
#pragma unroll
        for (int e = 0; e < EPT; ++e) {
            const unsigned cc = (e < 4 ? (c8lo >> (8 * e)) : (c8hi >> (8 * (e - 4)))) & 0xFFu;
            if (cc) atomicAdd(orow + GIDX(e), (float)cc * 0.01f);
        }
    }
}

// Sum 10 u8-packed partials per u32 slot (each byte <= 10, sum <= 100).
// Slot = tid*2 + w covers elements e = 4w..4w+3 -> gidx = w*4096 + t*4 + i.
__global__ __launch_bounds__(256) void reduce_kernel(
    const unsigned* __restrict__ ws, float* __restrict__ out) {
    const int g    = blockIdx.x * 256 + threadIdx.x;   // 0..262143
    const int b    = g >> 11;
    const int slot = g & 2047;
    const int t    = slot >> 1;
    const int w    = slot & 1;
    unsigned acc = 0;
    for (int c = 0; c < SPLIT; ++c)
        acc += ws[((size_t)(b * SPLIT + c) << 11) + slot];
    const float4 o = make_float4((float)(acc & 255u) * 0.01f,
                                 (float)((acc >> 8) & 255u) * 0.01f,
                                 (float)((acc >> 16) & 255u) * 0.01f,
                                 (float)(acc >> 24) * 0.01f);
    *reinterpret_cast<float4*>(out + (size_t)b * NN + w * 4096 + t * 4) = o;
}

extern "C" void kernel_launch(void* const* d_in, const int* in_sizes, int n_in,
                              void* d_out, int out_size, void* d_ws, size_t ws_size,
                              hipStream_t stream) {
    const float* logits  = (const float*)d_in[0];   // [128, 8192] f32
    const float* uniform = (const float*)d_in[1];   // [128, 100, 8192] f32
    float* out = (float*)d_out;                     // [128, 8192] f32

    const int grid = BB * SPLIT;                    // 1280 blocks
    const size_t elgBytes = (size_t)BB * NN * sizeof(float);            // 4 MB
    const size_t cntBytes = (size_t)grid * NT * 2 * sizeof(unsigned);   // 10.5 MB

    if (ws_size >= elgBytes + cntBytes) {
        float* elg = (float*)d_ws;
        unsigned* cnts = (unsigned*)((char*)d_ws + elgBytes);
        exp_kernel<<<(BB * NN / 4) / 256, 256, 0, stream>>>(logits, elg);
        gumbel_topk_kernel<0><<<grid, NT, 0, stream>>>(
            elg, uniform, cnts, nullptr);
        reduce_kernel<<<(BB * NN / 4) / 256, 256, 0, stream>>>(cnts, out);
    } else {
        hipMemsetAsync(out, 0, (size_t)out_size * sizeof(float), stream);
        gumbel_topk_kernel<1><<<grid, NT, 0, stream>>>(
            logits, uniform, nullptr, out);
    }
}

// Round 18
// 106.918 us; speedup vs baseline: 2.0245x; 1.8611x over previous
//
#include <hip/hip_runtime.h>

#define BB 128
#define NN 8192
#define SS 100
#define KK 512
#define SPLIT 50               // sample PAIRS per batch row (SPB=2)
#define NT 1024                // 16 waves
#define EPT 8                  // elements per thread per sample
#define CAND 256
#define NBIN 2048
#define NWAVE 16

#define GIDX(e) (((e) >> 2) * 4096 + tid * 4 + ((e) & 3))
#define LN2 0.69314718056f

// LDS-only barrier: waits DS ops but leaves global loads in flight
// (__syncthreads drains vmcnt(0) too — guide §5). sched_barrier stops the
// compiler hoisting LDS reads above the wait (guide rule #18).
__device__ __forceinline__ void lds_barrier() {
    asm volatile("s_waitcnt lgkmcnt(0)" ::: "memory");
    __builtin_amdgcn_s_barrier();
    __builtin_amdgcn_sched_barrier(0);
}

// q-key: q = (-ln(u+eps)+eps) * e^{-lg} = e^{-p}, monotone DECREASING in p.
// ONE transcendental per element-sample; e^{-lg} computed once per block
// (amortized over both samples) — bit-identical everywhere.
__device__ __forceinline__ float q_of(float u, float elg) {
    const float w = fmaf(__builtin_amdgcn_logf(u + 1e-20f), -LN2, 1e-20f);
    return w * elg;
}

// Monotone bin map via float bits (sign|exp8|mant7), flipped so HIGHER bin =
// HIGHER p. Window q in [2^-13,16) i.e. p in (-2.77, 9]; outside clamps, and
// clamped bins stay exact via the in-bin rank loop (exact q compares).
__device__ __forceinline__ int bin_of(float q) {
    const int t = (int)(__float_as_uint(q) >> 16);
    int b = 16639 - t;
    b = b < 0 ? 0 : b;
    return b > 2047 ? 2047 : b;
}

// One block = (b, pair of samples). 5 LDS barriers; global loads are never
// drained by a barrier. R14 structure with exp fused (no precompute pass).
// MODE 0: packed 2-bit counts (u16/thread) -> ws. MODE 1: atomicAdd out.
template <int MODE>
__global__ __launch_bounds__(NT, 8) void gumbel_topk_kernel(
    const float* __restrict__ logits,
    const float* __restrict__ uniform,
    unsigned short* __restrict__ ws,
    float* __restrict__ out) {

    __shared__ __align__(16) int histA[NBIN];
    __shared__ __align__(16) int histB[NBIN];
    __shared__ float ckA[CAND];
    __shared__ int   ciA[CAND];
    __shared__ float ckB[CAND];
    __shared__ int   ciB[CAND];
    __shared__ int waveTotA[NWAVE], waveTotB[NWAVE];
    __shared__ int bselA, bkkA, bselB, bkkB, cntA, cntB;

    const int tid  = threadIdx.x;
    const int lane = tid & 63;
    const int wv   = tid >> 6;
    const int b    = blockIdx.x / SPLIT;
    const int ch   = blockIdx.x % SPLIT;

    const float* lrow  = logits + (size_t)b * NN;
    const float* uArow = uniform + ((size_t)b * SS + ch * 2) * NN;
    const float* uBrow = uArow + NN;

    // ---- issue ALL global loads upfront; they stay in flight across s0
    float le[EPT], qA[EPT], qB[EPT];
#pragma unroll
    for (int j = 0; j < 2; ++j) {
        *reinterpret_cast<float4*>(&qA[j * 4]) =
            *reinterpret_cast<const float4*>(&uArow[j * 4096 + tid * 4]);
        *reinterpret_cast<float4*>(&qB[j * 4]) =
            *reinterpret_cast<const float4*>(&uBrow[j * 4096 + tid * 4]);
        *reinterpret_cast<float4*>(&le[j * 4]) =
            *reinterpret_cast<const float4*>(&lrow[j * 4096 + tid * 4]);
    }

    // ---- init LDS: 4096 ints over 1024 threads = one int4 each
    if (tid < 512) *reinterpret_cast<int4*>(&histA[tid * 4]) = make_int4(0, 0, 0, 0);
    else           *reinterpret_cast<int4*>(&histB[(tid - 512) * 4]) = make_int4(0, 0, 0, 0);
    if (tid == 0) { cntA = 0; cntB = 0; }
    lds_barrier();                                        // s0

    // ---- le = e^{-logit} (once per block; vmcnt waits happen here at use)
#pragma unroll
    for (int e = 0; e < EPT; ++e) le[e] = __expf(-le[e]);

    // ---- transform (1 log/elem) + histogram; q stays live in registers
#pragma unroll
    for (int e = 0; e < EPT; ++e) {
        qA[e] = q_of(qA[e], le[e]);
        qB[e] = q_of(qB[e], le[e]);
        atomicAdd(&histA[bin_of(qA[e])], 1);
        atomicAdd(&histB[bin_of(qB[e])], 1);
    }
    lds_barrier();                                        // s1

    // ---- cross-wave suffix scan of both hists (2 bins/thread); the
    // crossing thread broadcasts (sel, kk). 2 barriers.
    {
        const int base = tid * 2;
        const int2 hA = *reinterpret_cast<const int2*>(&histA[base]);
        const int2 hB = *reinterpret_cast<const int2*>(&histB[base]);
        const int sumA = hA.x + hA.y, sumB = hB.x + hB.y;
        int sufA = sumA, sufB = sumB;
#pragma unroll
        for (int d = 1; d < 64; d <<= 1) {
            const int oA = __shfl_down(sufA, d);
            const int oB = __shfl_down(sufB, d);
            if (lane + d < 64) { sufA += oA; sufB += oB; }
        }
        if (lane == 0) { waveTotA[wv] = sufA; waveTotB[wv] = sufB; }
        lds_barrier();                                    // s2
        int cumA = sufA - sumA, cumB = sufB - sumB;
        for (int w2 = wv + 1; w2 < NWAVE; ++w2) { cumA += waveTotA[w2]; cumB += waveTotB[w2]; }
        if (cumA < KK && cumA + hA.y >= KK) { bselA = base + 1; bkkA = KK - cumA; }
        cumA += hA.y;
        if (cumA < KK && cumA + hA.x >= KK) { bselA = base;     bkkA = KK - cumA; }
        if (cumB < KK && cumB + hB.y >= KK) { bselB = base + 1; bkkB = KK - cumB; }
        cumB += hB.y;
        if (cumB < KK && cumB + hB.x >= KK) { bselB = base;     bkkB = KK - cumB; }
        lds_barrier();                                    // s3
    }

    const int selA = bselA, kkA = bkkA;
    const int selB = bselB, kkB = bkkB;

    // ---- collect threshold-bin candidates (~3/sample; keys from live q)
#pragma unroll
    for (int e = 0; e < EPT; ++e) {
        if (bin_of(qA[e]) == selA) {
            const int pos = atomicAdd(&cntA, 1);
            if (pos < CAND) { ckA[pos] = qA[e]; ciA[pos] = GIDX(e); }
        }
        if (bin_of(qB[e]) == selB) {
            const int pos = atomicAdd(&cntB, 1);
            if (pos < CAND) { ckB[pos] = qB[e]; ciB[pos] = GIDX(e); }
        }
    }
    lds_barrier();                                        // s4

    // ---- membership: 2-bit count per element; in-bin elements rank by
    // (q asc = p desc, idx asc) — JAX tie-break.
    const int cA = cntA < CAND ? cntA : CAND;
    const int cB = cntB < CAND ? cntB : CAND;
    unsigned cnt8 = 0;
#pragma unroll
    for (int e = 0; e < EPT; ++e) {
        {
            const int bb = bin_of(qA[e]);
            if (bb > selA) {
                cnt8 += 1u << (2 * e);
            } else if (bb == selA) {
                const float kl = qA[e]; const int il = GIDX(e);
                int r = 0;
                for (int j = 0; j < cA; ++j)
                    r += (ckA[j] < kl || (ckA[j] == kl && ciA[j] < il)) ? 1 : 0;
                if (r < kkA) cnt8 += 1u << (2 * e);
            }
        }
        {
            const int bb = bin_of(qB[e]);
            if (bb > selB) {
                cnt8 += 1u << (2 * e);
            } else if (bb == selB) {
                const float kl = qB[e]; const int il = GIDX(e);
                int r = 0;
                for (int j = 0; j < cB; ++j)
                    r += (ckB[j] < kl || (ckB[j] == kl && ciB[j] < il)) ? 1 : 0;
                if (r < kkB) cnt8 += 1u << (2 * e);
            }
        }
    }

    if (MODE == 0) {
        ws[(size_t)blockIdx.x * NT + tid] = (unsigned short)cnt8;
    } else {
        float* orow = out + (size_t)b * NN;
#pragma unroll
        for (int e = 0; e < EPT; ++e) {
            const unsigned c = (cnt8 >> (2 * e)) & 3u;
            if (c) atomicAdd(orow + GIDX(e), (float)c * 0.01f);
        }
    }
}

// Sum 50 packed-2-bit partials per u16 position; each field <= 2, sum <= 100.
__global__ __launch_bounds__(256) void reduce_kernel(
    const unsigned short* __restrict__ ws, float* __restrict__ out) {
    const int g   = blockIdx.x * 256 + threadIdx.x;   // 0..131071
    const int b   = g >> 10;
    const int pos = g & 1023;
    int acc[8] = {0, 0, 0, 0, 0, 0, 0, 0};
    for (int ch = 0; ch < SPLIT; ++ch) {
        const unsigned w = ws[((size_t)(b * SPLIT + ch) << 10) + pos];
#pragma unroll
        for (int e = 0; e < 8; ++e) acc[e] += (w >> (2 * e)) & 3u;
    }
    float* ob = out + (size_t)b * NN;
    const float4 o0 = make_float4(acc[0] * 0.01f, acc[1] * 0.01f,
                                  acc[2] * 0.01f, acc[3] * 0.01f);
    const float4 o1 = make_float4(acc[4] * 0.01f, acc[5] * 0.01f,
                                  acc[6] * 0.01f, acc[7] * 0.01f);
    *reinterpret_cast<float4*>(&ob[pos * 4])        = o0;
    *reinterpret_cast<float4*>(&ob[4096 + pos * 4]) = o1;
}

extern "C" void kernel_launch(void* const* d_in, const int* in_sizes, int n_in,
                              void* d_out, int out_size, void* d_ws, size_t ws_size,
                              hipStream_t stream) {
    const float* logits  = (const float*)d_in[0];   // [128, 8192] f32
    const float* uniform = (const float*)d_in[1];   // [128, 100, 8192] f32
    float* out = (float*)d_out;                     // [128, 8192] f32

    const int grid = BB * SPLIT;                    // 6400 blocks
    const size_t cntBytes = (size_t)grid * NT * sizeof(unsigned short); // 13 MB

    if (ws_size >= cntBytes) {
        gumbel_topk_kernel<0><<<grid, NT, 0, stream>>>(
            logits, uniform, (unsigned short*)d_ws, nullptr);
        reduce_kernel<<<(BB * NN / 8) / 256, 256, 0, stream>>>(
            (const unsigned short*)d_ws, out);
    } else {
        hipMemsetAsync(out, 0, (size_t)out_size * sizeof(float), stream);
        gumbel_topk_kernel<1><<<grid, NT, 0, stream>>>(
            logits, uniform, nullptr, out);
    }
}